// Round 1
// baseline (7556.414 us; speedup 1.0000x reference)
//
#include <hip/hip_runtime.h>

#define NB 32
#define NT 512
#define NI 512
#define NH 512
#define NG 2048
#define GH (NG*NH)  // 1048576, power of 2

// ---- ws layout (bytes) ----
#define SZ_WHH    ((size_t)NB*NG*NH*2)            // 64 MB  gated Whh bf16 [B][G][H]
#define OFF_XPROJ (SZ_WHH)
#define SZ_XPROJ  ((size_t)NB*NT*NG*2)            // 64 MB  x_proj bf16 [B][T][G]
#define OFF_BIAS  (OFF_XPROJ + SZ_XPROJ)
#define SZ_BIAS   ((size_t)NB*NG*4)               // 256 KB fp32 bias [B][G]
#define OFF_H     (OFF_BIAS + SZ_BIAS)
#define SZ_H      ((size_t)2*NB*NH*4)             // double-buffered fp32 h
#define OFF_C     (OFF_H + SZ_H)
#define SZ_C      ((size_t)NB*NH*4)               // fp32 c

__device__ __forceinline__ float bf2f(unsigned short u) {
    union { unsigned int i; float f; } v; v.i = ((unsigned int)u) << 16; return v.f;
}
__device__ __forceinline__ unsigned short f2bf(float f) {
    union { unsigned int i; float f; } v; v.f = f;
    unsigned int r = v.i + 0x7FFFu + ((v.i >> 16) & 1u);  // RNE
    return (unsigned short)(r >> 16);
}
// z = clip(1.2*sigmoid(1.5*(log(eps)-log(1-eps)+m)) - 0.1, 0, 1)
__device__ __forceinline__ float gate_z(float eps, float m) {
    float u = (__logf(eps) - __logf(1.0f - eps) + m) * 1.5f;
    float y = 1.0f / (1.0f + __expf(-u));
    float z = fmaf(y, 1.2f, -0.1f);
    return fminf(fmaxf(z, 0.0f), 1.0f);
}
__device__ __forceinline__ float sigmoidf_(float x) {
    return 1.0f / (1.0f + __expf(-x));
}

// ---------- Kernel 1: gated Whh -> bf16 [B][G][H] ----------
__global__ __launch_bounds__(256) void k_gate_hh(
    const float* __restrict__ eps, const float* __restrict__ mask,
    const float* __restrict__ w, unsigned short* __restrict__ out) {
    int idx  = blockIdx.x * 256 + threadIdx.x;   // 4,194,304 threads
    int base = idx << 3;                         // 8 elems/thread
    int gk   = base & (GH - 1);                  // index into mask/w (no batch dim)
    float4 e0 = *(const float4*)(eps + base);
    float4 e1 = *(const float4*)(eps + base + 4);
    float4 m0 = *(const float4*)(mask + gk);
    float4 m1 = *(const float4*)(mask + gk + 4);
    float4 w0 = *(const float4*)(w + gk);
    float4 w1 = *(const float4*)(w + gk + 4);
    union { uint4 v; unsigned short s[8]; } o;
    o.s[0] = f2bf(gate_z(e0.x, m0.x) * w0.x);
    o.s[1] = f2bf(gate_z(e0.y, m0.y) * w0.y);
    o.s[2] = f2bf(gate_z(e0.z, m0.z) * w0.z);
    o.s[3] = f2bf(gate_z(e0.w, m0.w) * w0.w);
    o.s[4] = f2bf(gate_z(e1.x, m1.x) * w1.x);
    o.s[5] = f2bf(gate_z(e1.y, m1.y) * w1.y);
    o.s[6] = f2bf(gate_z(e1.z, m1.z) * w1.z);
    o.s[7] = f2bf(gate_z(e1.w, m1.w) * w1.w);
    *(uint4*)(out + base) = o.v;
}

// ---------- Kernel 2: bias[b][g] = z(eps_bih)*b_ih + z(eps_bhh)*b_hh ----------
__global__ __launch_bounds__(256) void k_bias(
    const float* __restrict__ eb1, const float* __restrict__ eb2,
    const float* __restrict__ mb1, const float* __restrict__ mb2,
    const float* __restrict__ b1, const float* __restrict__ b2,
    float* __restrict__ bias) {
    int idx = blockIdx.x * 256 + threadIdx.x;    // B*G = 65536
    int g = idx & (NG - 1);
    bias[idx] = gate_z(eb1[idx], mb1[g]) * b1[g] + gate_z(eb2[idx], mb2[g]) * b2[g];
}

// ---------- Kernel 3: x_proj[b][t][g] = bias + sum_i seq[b,t,i]*z_ih*w_ih ----------
// tile: 128 t-rows x 64 g-cols, K-chunk 32; gating fused (Wih never materialized)
__global__ __launch_bounds__(256) void k_xproj(
    const float* __restrict__ seq, const float* __restrict__ eps_ih,
    const float* __restrict__ mask_ih, const float* __restrict__ w_ih,
    const float* __restrict__ bias, unsigned short* __restrict__ xproj) {
    __shared__ float As[128 * 33];   // [t][i], +1 pad
    __shared__ float Ws[32 * 68];    // [i][g], stride 68 -> 16B-aligned float4 rows
    int g0 = blockIdx.x * 64;
    int t0 = blockIdx.y * 128;
    int b  = blockIdx.z;
    int tid = threadIdx.x;
    int gq = tid & 15;    // g sub-block of 4
    int rq = tid >> 4;    // t rows rq + 16k
    float acc[4][8];
#pragma unroll
    for (int c = 0; c < 4; ++c)
#pragma unroll
        for (int k = 0; k < 8; ++k) acc[c][k] = 0.0f;

    for (int i0 = 0; i0 < NI; i0 += 32) {
        __syncthreads();
        // stage A-tile: 128x32 fp32, float4 loads
#pragma unroll
        for (int k = 0; k < 4; ++k) {
            int e = (tid + (k << 8)) << 2;
            int r = e >> 5, c = e & 31;
            float4 v = *(const float4*)(seq + (b * NT + t0 + r) * NI + i0 + c);
            As[r * 33 + c    ] = v.x;
            As[r * 33 + c + 1] = v.y;
            As[r * 33 + c + 2] = v.z;
            As[r * 33 + c + 3] = v.w;
        }
        // stage gated W-tile: 64g x 32i, stored transposed [i][g]
#pragma unroll
        for (int k = 0; k < 2; ++k) {
            int e = (tid + (k << 8)) << 2;
            int gr = e >> 5, c = e & 31;
            int mo = (g0 + gr) * NI + i0 + c;
            int eo = b * GH + mo;
            float4 ev = *(const float4*)(eps_ih + eo);
            float4 mv = *(const float4*)(mask_ih + mo);
            float4 wv = *(const float4*)(w_ih + mo);
            Ws[(c    ) * 68 + gr] = gate_z(ev.x, mv.x) * wv.x;
            Ws[(c + 1) * 68 + gr] = gate_z(ev.y, mv.y) * wv.y;
            Ws[(c + 2) * 68 + gr] = gate_z(ev.z, mv.z) * wv.z;
            Ws[(c + 3) * 68 + gr] = gate_z(ev.w, mv.w) * wv.w;
        }
        __syncthreads();
#pragma unroll 4
        for (int i = 0; i < 32; ++i) {
            float4 wv = *(const float4*)&Ws[i * 68 + (gq << 2)];
#pragma unroll
            for (int k = 0; k < 8; ++k) {
                float av = As[(rq + (k << 4)) * 33 + i];
                acc[0][k] = fmaf(wv.x, av, acc[0][k]);
                acc[1][k] = fmaf(wv.y, av, acc[1][k]);
                acc[2][k] = fmaf(wv.z, av, acc[2][k]);
                acc[3][k] = fmaf(wv.w, av, acc[3][k]);
            }
        }
    }
    // epilogue: add bias, store bf16 (uint2 = 4 bf16 per store)
    float bs[4];
#pragma unroll
    for (int c = 0; c < 4; ++c) bs[c] = bias[b * NG + g0 + (gq << 2) + c];
#pragma unroll
    for (int k = 0; k < 8; ++k) {
        int r = t0 + rq + (k << 4);
        unsigned short* op = xproj + (b * NT + r) * NG + g0 + (gq << 2);
        union { uint2 v; unsigned short s[4]; } o;
        o.s[0] = f2bf(acc[0][k] + bs[0]);
        o.s[1] = f2bf(acc[1][k] + bs[1]);
        o.s[2] = f2bf(acc[2][k] + bs[2]);
        o.s[3] = f2bf(acc[3][k] + bs[3]);
        *(uint2*)op = o.v;
    }
}

// ---------- Kernel 4: one recurrence step. One wave per (b, j). ----------
__global__ __launch_bounds__(256) void k_step(
    const unsigned short* __restrict__ whh,   // [B][G][H] bf16
    const unsigned short* __restrict__ xproj, // [B][T][G] bf16
    const float* __restrict__ hsrc, float* __restrict__ hdst,
    float* __restrict__ cbuf, float* __restrict__ out, int t) {
    int widx = (blockIdx.x << 2) + (threadIdx.x >> 6); // global wave id
    int lane = threadIdx.x & 63;
    int b = widx >> 9;       // /512
    int j = widx & 511;
    // each lane holds 8 h values (k = lane*8 .. +8)
    const float* hp = hsrc + b * NH + (lane << 3);
    float4 h0 = *(const float4*)hp;
    float4 h1 = *(const float4*)(hp + 4);
    float hr[8] = {h0.x, h0.y, h0.z, h0.w, h1.x, h1.y, h1.z, h1.w};
    float acc[4];
#pragma unroll
    for (int q = 0; q < 4; ++q) {  // gates i,f,g,o = rows j + 512q
        const unsigned short* wp = whh + (b * NG + (q << 9) + j) * NH + (lane << 3);
        union { uint4 v; unsigned short s[8]; } wv;
        wv.v = *(const uint4*)wp;   // 16B/lane, coalesced 1KB/row
        float a = 0.0f;
#pragma unroll
        for (int u = 0; u < 8; ++u) a = fmaf(bf2f(wv.s[u]), hr[u], a);
        acc[q] = a;
    }
#pragma unroll
    for (int off = 32; off > 0; off >>= 1) {
        acc[0] += __shfl_xor(acc[0], off);
        acc[1] += __shfl_xor(acc[1], off);
        acc[2] += __shfl_xor(acc[2], off);
        acc[3] += __shfl_xor(acc[3], off);
    }
    if (lane == 0) {
        const unsigned short* xp = xproj + (b * NT + t) * NG + j;
        float gi = acc[0] + bf2f(xp[0]);
        float gf = acc[1] + bf2f(xp[512]);
        float gg = acc[2] + bf2f(xp[1024]);
        float go = acc[3] + bf2f(xp[1536]);
        int hj = b * NH + j;
        float cold = cbuf[hj];
        float cn = fmaf(sigmoidf_(gf), cold, sigmoidf_(gi) * tanhf(gg));
        float hn = sigmoidf_(go) * tanhf(cn);
        cbuf[hj] = cn;
        hdst[hj] = hn;
        out[(b * NT + t) * NH + j] = hn;
        if (t == NT - 1) {
            out[NB * NT * NH + hj] = hn;            // h_n
            out[NB * NT * NH + NB * NH + hj] = cn;  // c_n
        }
    }
}

extern "C" void kernel_launch(void* const* d_in, const int* in_sizes, int n_in,
                              void* d_out, int out_size, void* d_ws, size_t ws_size,
                              hipStream_t stream) {
    const float* seq      = (const float*)d_in[0];
    const float* w_ih     = (const float*)d_in[1];
    const float* w_hh     = (const float*)d_in[2];
    const float* b_ih     = (const float*)d_in[3];
    const float* b_hh     = (const float*)d_in[4];
    const float* mask_ih  = (const float*)d_in[5];
    const float* mask_hh  = (const float*)d_in[6];
    const float* mask_bih = (const float*)d_in[7];
    const float* mask_bhh = (const float*)d_in[8];
    const float* eps_ih   = (const float*)d_in[9];
    const float* eps_hh   = (const float*)d_in[10];
    const float* eps_bih  = (const float*)d_in[11];
    const float* eps_bhh  = (const float*)d_in[12];

    char* ws = (char*)d_ws;
    unsigned short* whh   = (unsigned short*)(ws);
    unsigned short* xproj = (unsigned short*)(ws + OFF_XPROJ);
    float* bias = (float*)(ws + OFF_BIAS);
    float* hbuf = (float*)(ws + OFF_H);
    float* cbuf = (float*)(ws + OFF_C);
    float* out  = (float*)d_out;

    // h0 = 0 (only ping buffer needed), c0 = 0; ws is poisoned 0xAA
    hipMemsetAsync(hbuf, 0, (size_t)NB * NH * 4, stream);
    hipMemsetAsync(cbuf, 0, (size_t)NB * NH * 4, stream);

    k_gate_hh<<<dim3(16384), dim3(256), 0, stream>>>(eps_hh, mask_hh, w_hh, whh);
    k_bias<<<dim3(256), dim3(256), 0, stream>>>(eps_bih, eps_bhh, mask_bih, mask_bhh,
                                                b_ih, b_hh, bias);
    k_xproj<<<dim3(NG / 64, NT / 128, NB), dim3(256), 0, stream>>>(
        seq, eps_ih, mask_ih, w_ih, bias, xproj);

    for (int t = 0; t < NT; ++t) {
        const float* hs = hbuf + (t & 1) * (NB * NH);
        float* hd = hbuf + ((t + 1) & 1) * (NB * NH);
        k_step<<<dim3(NB * NH / 4), dim3(256), 0, stream>>>(whh, xproj, hs, hd,
                                                            cbuf, out, t);
    }
}